// Round 7
// baseline (1176.584 us; speedup 1.0000x reference)
//
#include <hip/hip_runtime.h>
#include <hip/hip_bf16.h>

typedef float f32x4 __attribute__((ext_vector_type(4)));
typedef short short8 __attribute__((ext_vector_type(8)));
typedef __hip_bfloat16 bf16;

constexpr int CDIM  = 384;
constexpr int LTOK  = 3136;      // 56*56
constexpr int NWIN  = 2048;      // 32 * 64 windows
constexpr int MROWS = 100352;    // NWIN * 49 = 784 panels x 128 rows
constexpr int MPAD  = MROWS + 64;
constexpr int NP128 = 784;       // 128-row panels

__device__ __forceinline__ void gload_lds16(const void* g, void* l) {
  __builtin_amdgcn_global_load_lds(
      (const __attribute__((address_space(1))) void*)g,
      (__attribute__((address_space(3))) void*)l, 16, 0, 0);
}

// window-row r (w*49+n) -> (batch b, token l)
__device__ __forceinline__ void row_to_bl(int r, int& b, int& l) {
  int w = r / 49, n = r % 49;
  b = w >> 6;
  int wrem = w & 63;
  int wy = wrem >> 3, wx = wrem & 7;
  int ny = n / 7, nx = n % 7;
  l = (wy * 7 + ny) * 56 + wx * 7 + nx;
}

// ---------------- fused prep: mod GEMV | W retile (32-col slices) | bias table ----------------
// W tiled layout, flat elem per matrix:
//   i = s*12288 + (kt*4+g)*256 + ni*128 + r16*8 + j8
//   holds W[k = kt*32 + g*8 + j8][n = s*32 + ni*16 + r16]   (slice = 24 KB)

__global__ __launch_bounds__(256) void prep_all(
    const float* __restrict__ cond, const float* __restrict__ mw,
    const float* __restrict__ mb, float* __restrict__ mod,
    const float* __restrict__ qw, const float* __restrict__ kvw,
    const float* __restrict__ pw,
    bf16* __restrict__ wtq, bf16* __restrict__ wtkv, bf16* __restrict__ wtp,
    const float* __restrict__ tab, float* __restrict__ bT) {
  int bid = blockIdx.x, t = threadIdx.x;
  if (bid < 96) {                               // mod = cond @ mod_w + mod_b
    int idx = bid * 256 + t;                    // 24576 exact
    int b = idx / 768, j = idx % 768;
    float s = mb[j];
    const float* cr = cond + b * 128;
    #pragma unroll 4
    for (int k = 0; k < 128; k++) s += cr[k] * mw[(size_t)k * 768 + j];
    mod[idx] = s;
  } else if (bid < 2400) {                      // weight retile, 589824 exact
    int idx = (bid - 96) * 256 + t;
    const float* src; bf16* dst; int i, Wn;
    if (idx < 147456)      { i = idx;          src = qw;  dst = wtq;  Wn = 384; }
    else if (idx < 442368) { i = idx - 147456; src = kvw; dst = wtkv; Wn = 768; }
    else                   { i = idx - 442368; src = pw;  dst = wtp;  Wn = 384; }
    int s = i / 12288, rem = i % 12288;
    int u = rem >> 8, v = rem & 255;
    int ni = v >> 7, r16 = (v >> 3) & 15, j8 = v & 7;
    int kt = u >> 2, g = u & 3;
    int k = kt * 32 + g * 8 + j8, n = s * 32 + ni * 16 + r16;
    dst[i] = __float2bfloat16(src[(size_t)k * Wn + n]);
  } else {                                      // biasT[h][m][c], 49152 exact
    int idx = (bid - 2400) * 256 + t;
    int h = idx >> 12, rem = idx & 4095, m = rem >> 6, c = rem & 63;
    float v;
    if (c >= 49)      v = -1e30f;
    else if (m >= 49) v = 0.f;
    else {
      int yq = m / 7, xq = m % 7, yk = c / 7, xk = c % 7;
      v = tab[((yq - yk + 6) * 13 + (xq - xk + 6)) * 12 + h];
    }
    bT[idx] = v;
  }
}

// ---------------- LayerNorm (+AdaLN for x), row-major bf16 out, both streams ----------------

struct alignas(8) B4 { bf16 h[4]; };

__global__ __launch_bounds__(256) void ln_both(
    const float* __restrict__ x_tok, const float* __restrict__ gx,
    const float* __restrict__ bx, const float* __restrict__ modbuf,
    const float* __restrict__ z_tok, const float* __restrict__ gz,
    const float* __restrict__ bz,
    bf16* __restrict__ xO, bf16* __restrict__ zO) {
  int bid = blockIdx.x;
  bool isX = bid < 25088;
  const float* src   = isX ? x_tok : z_tok;
  const float* gamma = isX ? gx : gz;
  const float* beta  = isX ? bx : bz;
  const float* mod   = isX ? modbuf : nullptr;
  bf16* dst          = isX ? xO : zO;
  float eps          = isX ? 1e-6f : 1e-5f;
  int rb = (isX ? bid : bid - 25088) * 4;

  int wid = threadIdx.x >> 6, lane = threadIdx.x & 63;
  int r = rb + wid;
  int bb, ll; row_to_bl(r, bb, ll);
  const f32x4* x4 = (const f32x4*)(src + ((size_t)bb * LTOK + ll) * 384);
  f32x4 a = x4[lane];
  f32x4 b = {0.f, 0.f, 0.f, 0.f};
  if (lane < 32) b = x4[64 + lane];
  float s  = a[0] + a[1] + a[2] + a[3] + b[0] + b[1] + b[2] + b[3];
  float s2 = a[0]*a[0] + a[1]*a[1] + a[2]*a[2] + a[3]*a[3]
           + b[0]*b[0] + b[1]*b[1] + b[2]*b[2] + b[3]*b[3];
  #pragma unroll
  for (int d = 1; d < 64; d <<= 1) { s += __shfl_xor(s, d); s2 += __shfl_xor(s2, d); }
  float mu = s * (1.f / 384.f);
  float var = s2 * (1.f / 384.f) - mu * mu;
  float rstd = rsqrtf(var + eps);
  bf16* o = dst + (size_t)r * 384;
  const f32x4* g4 = (const f32x4*)gamma;
  const f32x4* be4 = (const f32x4*)beta;
  if (mod != nullptr) {
    const f32x4* mg4 = (const f32x4*)(mod + bb * 768);
    const f32x4* mb4 = (const f32x4*)(mod + bb * 768 + 384);
    {
      f32x4 gg = g4[lane], bb2 = be4[lane], mg = mg4[lane], mb = mb4[lane];
      B4 p;
      #pragma unroll
      for (int i = 0; i < 4; i++)
        p.h[i] = __float2bfloat16((gg[i] * (1.f + mg[i])) * ((a[i] - mu) * rstd) + bb2[i] + mb[i]);
      *((B4*)o + lane) = p;
    }
    if (lane < 32) {
      f32x4 gg = g4[64 + lane], bb2 = be4[64 + lane], mg = mg4[64 + lane], mb = mb4[64 + lane];
      B4 p;
      #pragma unroll
      for (int i = 0; i < 4; i++)
        p.h[i] = __float2bfloat16((gg[i] * (1.f + mg[i])) * ((b[i] - mu) * rstd) + bb2[i] + mb[i]);
      *((B4*)o + 64 + lane) = p;
    }
  } else {
    {
      f32x4 gg = g4[lane], bb2 = be4[lane];
      B4 p;
      #pragma unroll
      for (int i = 0; i < 4; i++)
        p.h[i] = __float2bfloat16((a[i] - mu) * rstd * gg[i] + bb2[i]);
      *((B4*)o + lane) = p;
    }
    if (lane < 32) {
      f32x4 gg = g4[64 + lane], bb2 = be4[64 + lane];
      B4 p;
      #pragma unroll
      for (int i = 0; i < 4; i++)
        p.h[i] = __float2bfloat16((b[i] - mu) * rstd * gg[i] + bb2[i]);
      *((B4*)o + 64 + lane) = p;
    }
  }
}

// ---------------- GEMM v7: 32-col W-slice in LDS; cohort->XCD pinned A sharing ----------------
// Cohort c = NS blocks covering all N cols of the same rows, pinned to XCD c%8 so A is
// fetched from HBM once per cohort and shared via that XCD's L2.
// grid = 1536 (6 blocks/CU exactly, one round). No barriers in the main loop.
// MODE 0: bf16 (acc+bias)*scale   MODE 1: f32 resid + window-unpermute

template<int MODE>
__global__ __launch_bounds__(256, 6) void gemm7(
    const bf16* __restrict__ A, const bf16* __restrict__ WTt,
    const float* __restrict__ bias, void* __restrict__ outp,
    const float* __restrict__ resid, float scale, int N, int NS, int NC) {
  __shared__ __align__(16) bf16 wS[12288];      // 32 cols x 384 k, MFMA-tiled (24 KB)
  const int t = threadIdx.x;
  const int wid = t >> 6, lane = t & 63;
  const int r16 = lane & 15, g = lane >> 4;
  // cohort mapping: bid = x + 8*( (c/8)*NS + j ), XCD(bid) = bid%8 = c%8
  const int x = blockIdx.x & 7, i = blockIdx.x >> 3;
  const int s = i % NS;                         // slice (which 32 cols)
  const int c = (i / NS) * 8 + x;               // cohort (which rows)

  {
    const char* src = (const char*)WTt + (size_t)s * 24576;
    #pragma unroll
    for (int k = 0; k < 6; k++)
      gload_lds16(src + (k * 256 + t) * 16, (char*)wS + (k * 256 + t) * 16);
  }
  const float bc0 = bias[s * 32 + r16];
  const float bc1 = bias[s * 32 + 16 + r16];
  __syncthreads();                              // W resident; LDS read-only hereafter

  for (int p = c; p < NP128; p += NC) {
    const int prow = p * 128 + wid * 32;        // wave owns 32 rows x 32 cols
    const bf16* Ab = A + (size_t)prow * 384;

    f32x4 acc[2][2] = {};
    #pragma unroll
    for (int kt = 0; kt < 12; kt++) {
      short8 a0 = *(const short8*)(Ab + (size_t)r16 * 384 + kt * 32 + g * 8);
      short8 a1 = *(const short8*)(Ab + (size_t)(16 + r16) * 384 + kt * 32 + g * 8);
      short8 w0 = *(const short8*)((const char*)wS + (kt * 4 + g) * 512 + r16 * 16);
      short8 w1 = *(const short8*)((const char*)wS + (kt * 4 + g) * 512 + 256 + r16 * 16);
      acc[0][0] = __builtin_amdgcn_mfma_f32_16x16x32_bf16(a0, w0, acc[0][0], 0, 0, 0);
      acc[0][1] = __builtin_amdgcn_mfma_f32_16x16x32_bf16(a0, w1, acc[0][1], 0, 0, 0);
      acc[1][0] = __builtin_amdgcn_mfma_f32_16x16x32_bf16(a1, w0, acc[1][0], 0, 0, 0);
      acc[1][1] = __builtin_amdgcn_mfma_f32_16x16x32_bf16(a1, w1, acc[1][1], 0, 0, 0);
    }

    if (MODE == 0) {
      bf16* O = (bf16*)outp;
      #pragma unroll
      for (int m = 0; m < 2; m++) {
        #pragma unroll
        for (int rr = 0; rr < 4; rr++) {
          size_t rbase = (size_t)(prow + m * 16 + g * 4 + rr) * N + s * 32;
          O[rbase + r16]      = __float2bfloat16((acc[m][0][rr] + bc0) * scale);
          O[rbase + 16 + r16] = __float2bfloat16((acc[m][1][rr] + bc1) * scale);
        }
      }
    } else {
      float* O = (float*)outp;
      #pragma unroll
      for (int m = 0; m < 2; m++) {
        #pragma unroll
        for (int rr = 0; rr < 4; rr++) {
          int row = prow + m * 16 + g * 4 + rr;
          int bb, ll; row_to_bl(row, bb, ll);
          size_t base = ((size_t)bb * LTOK + ll) * 384 + s * 32;
          O[base + r16]      = resid[base + r16]      + acc[m][0][rr] + bc0;
          O[base + 16 + r16] = resid[base + 16 + r16] + acc[m][1][rr] + bc1;
        }
      }
    }
  }
}

// ---------------- attention: one wave per (window, head), row-major out ----------------

__global__ __launch_bounds__(64) void attn_kernel(
    const bf16* __restrict__ q, const bf16* __restrict__ kv,
    const float* __restrict__ biasT, bf16* __restrict__ o) {
  __shared__ __align__(16) bf16 vt[32][72];   // V^T, padded
  __shared__ __align__(16) bf16 P[64][72];    // probs, padded
  const int h = blockIdx.x, w = blockIdx.y;
  const int lane = threadIdx.x;
  const int r16 = lane & 15, g = lane >> 4;
  const size_t qbase = (size_t)w * 49 * 384 + h * 32;
  const size_t kvbase = (size_t)w * 49 * 768 + h * 32;

  // zero vt (pad cols must be 0, LDS is uninitialized), then fill V^T
  for (int e = lane; e < 32 * 72; e += 64) ((bf16*)vt)[e] = __float2bfloat16(0.f);
  for (int e = lane; e < 49 * 32; e += 64) {
    int c = e >> 5, d = e & 31;
    vt[d][c] = kv[kvbase + (size_t)c * 768 + 384 + d];
  }

  // QK^T: A and B fragments straight from global (both k-contiguous)
  short8 aq[4], bk[4];
  #pragma unroll
  for (int mi = 0; mi < 4; mi++)
    aq[mi] = *(const short8*)(q + qbase + (size_t)(mi * 16 + r16) * 384 + g * 8);
  #pragma unroll
  for (int ni = 0; ni < 4; ni++)
    bk[ni] = *(const short8*)(kv + kvbase + (size_t)(ni * 16 + r16) * 768 + g * 8);

  f32x4 zero = {0.f, 0.f, 0.f, 0.f};
  f32x4 S[4][4];
  #pragma unroll
  for (int mi = 0; mi < 4; mi++)
    #pragma unroll
    for (int ni = 0; ni < 4; ni++)
      S[mi][ni] = __builtin_amdgcn_mfma_f32_16x16x32_bf16(aq[mi], bk[ni], zero, 0, 0, 0);

  // bias + softmax (rows split over 16-lane groups; cols>=49 get -1e30 from biasT)
  const float* bt = biasT + h * 4096;
  #pragma unroll
  for (int mi = 0; mi < 4; mi++) {
    #pragma unroll
    for (int r = 0; r < 4; r++) {
      int rowm = mi * 16 + g * 4 + r;
      float sv[4];
      #pragma unroll
      for (int ni = 0; ni < 4; ni++)
        sv[ni] = S[mi][ni][r] + bt[rowm * 64 + ni * 16 + r16];
      float mx = fmaxf(fmaxf(sv[0], sv[1]), fmaxf(sv[2], sv[3]));
      #pragma unroll
      for (int d = 1; d < 16; d <<= 1) mx = fmaxf(mx, __shfl_xor(mx, d));
      float sum = 0.f;
      #pragma unroll
      for (int ni = 0; ni < 4; ni++) { sv[ni] = __expf(sv[ni] - mx); sum += sv[ni]; }
      #pragma unroll
      for (int d = 1; d < 16; d <<= 1) sum += __shfl_xor(sum, d);
      float inv = __fdividef(1.f, sum);
      #pragma unroll
      for (int ni = 0; ni < 4; ni++)
        P[rowm][ni * 16 + r16] = __float2bfloat16(sv[ni] * inv);
    }
  }
  __syncthreads();

  // PV
  f32x4 acc[4][2] = {};
  #pragma unroll
  for (int c0 = 0; c0 < 2; c0++) {
    short8 ap[4], bv[2];
    #pragma unroll
    for (int mi = 0; mi < 4; mi++)
      ap[mi] = *(const short8*)((const char*)&P[0][0] + (mi * 16 + r16) * 144 + c0 * 64 + g * 16);
    #pragma unroll
    for (int di = 0; di < 2; di++)
      bv[di] = *(const short8*)((const char*)&vt[0][0] + (di * 16 + r16) * 144 + c0 * 64 + g * 16);
    #pragma unroll
    for (int mi = 0; mi < 4; mi++)
      #pragma unroll
      for (int di = 0; di < 2; di++)
        acc[mi][di] = __builtin_amdgcn_mfma_f32_16x16x32_bf16(ap[mi], bv[di], acc[mi][di], 0, 0, 0);
  }

  #pragma unroll
  for (int mi = 0; mi < 4; mi++) {
    #pragma unroll
    for (int r = 0; r < 4; r++) {
      int m = mi * 16 + g * 4 + r;
      if (m < 49) {
        #pragma unroll
        for (int di = 0; di < 2; di++)
          o[(size_t)(w * 49 + m) * 384 + h * 32 + di * 16 + r16] =
              __float2bfloat16(acc[mi][di][r]);
      }
    }
  }
}

// ---------------- launch ----------------

extern "C" void kernel_launch(void* const* d_in, const int* in_sizes, int n_in,
                              void* d_out, int out_size, void* d_ws, size_t ws_size,
                              hipStream_t stream) {
  (void)in_sizes; (void)n_in; (void)out_size; (void)ws_size;
  const float* x_tok   = (const float*)d_in[0];
  const float* z_tok   = (const float*)d_in[1];
  const float* cond    = (const float*)d_in[2];
  const float* gamma_x = (const float*)d_in[3];
  const float* beta_x  = (const float*)d_in[4];
  const float* mod_w   = (const float*)d_in[5];
  const float* mod_b   = (const float*)d_in[6];
  const float* gamma_z = (const float*)d_in[7];
  const float* beta_z  = (const float*)d_in[8];
  const float* rel_tab = (const float*)d_in[9];
  const float* q_w     = (const float*)d_in[10];
  const float* q_b     = (const float*)d_in[11];
  const float* kv_w    = (const float*)d_in[12];
  const float* kv_b    = (const float*)d_in[13];
  const float* proj_w  = (const float*)d_in[14];
  const float* proj_b  = (const float*)d_in[15];

  char* ws = (char*)d_ws;
  float* modbuf = (float*)(ws + 0);                          //  98304 B
  bf16*  wtq    = (bf16*)(ws + 98304);                       // 294912 B  (12 slices)
  bf16*  wtkv   = (bf16*)(ws + 98304 + 294912);              // 589824 B  (24 slices)
  bf16*  wtp    = (bf16*)(ws + 98304 + 294912 + 589824);     // 294912 B  (12 slices)
  float* biasT  = (float*)(ws + 98304 + 294912 + 589824 + 294912); // 196608 B
  char*  R1     = ws + 1474560;                              // x_hat -> attn_out (row-major)
  char*  R2     = R1 + (size_t)MPAD * 384 * 2;               // q row-major (+pad)
  char*  R3     = R2 + (size_t)MPAD * 384 * 2;               // kv row-major (+pad)
  char*  R4     = R3 + (size_t)MPAD * 768 * 2;               // z_hat row-major

  // zero pad rows (attention fragment loads read past the last window)
  hipMemsetAsync(R2 + (size_t)MROWS * 384 * 2, 0, 64 * 384 * 2, stream);
  hipMemsetAsync(R3 + (size_t)MROWS * 768 * 2, 0, 64 * 768 * 2, stream);

  prep_all<<<2592, 256, 0, stream>>>(cond, mod_w, mod_b, modbuf,
                                     q_w, kv_w, proj_w, wtq, wtkv, wtp,
                                     rel_tab, biasT);
  ln_both<<<50176, 256, 0, stream>>>(x_tok, gamma_x, beta_x, modbuf,
                                     z_tok, gamma_z, beta_z,
                                     (bf16*)R1, (bf16*)R4);
  gemm7<0><<<1536, 256, 0, stream>>>(
      (const bf16*)R1, wtq, q_b, R2, nullptr, 0.17677669529663687f, 384, 12, 128);
  gemm7<0><<<1536, 256, 0, stream>>>(
      (const bf16*)R4, wtkv, kv_b, R3, nullptr, 1.0f, 768, 24, 64);
  attn_kernel<<<dim3(12, NWIN), 64, 0, stream>>>(
      (const bf16*)R2, (const bf16*)R3, biasT, (bf16*)R1);
  gemm7<1><<<1536, 256, 0, stream>>>(
      (const bf16*)R1, wtp, proj_b, d_out, x_tok, 1.0f, 384, 12, 128);
}

// Round 8
// 806.328 us; speedup vs baseline: 1.4592x; 1.4592x over previous
//
#include <hip/hip_runtime.h>
#include <hip/hip_bf16.h>

typedef float f32x4 __attribute__((ext_vector_type(4)));
typedef short short8 __attribute__((ext_vector_type(8)));
typedef __hip_bfloat16 bf16;

constexpr int LTOK  = 3136;      // 56*56
constexpr int NWIN  = 2048;
constexpr int MROWS = 100352;    // NWIN * 49

#define MFMA(a, b, c) __builtin_amdgcn_mfma_f32_16x16x32_bf16((a), (b), (c), 0, 0, 0)

// window-row r (w*49+n) -> (batch b, token l)
__device__ __forceinline__ void row_to_bl(int r, int& b, int& l) {
  int w = r / 49, n = r % 49;
  b = w >> 6;
  int wrem = w & 63;
  int wy = wrem >> 3, wx = wrem & 7;
  int ny = n / 7, nx = n % 7;
  l = (wy * 7 + ny) * 56 + wx * 7 + nx;
}

// ---------------- fused prep: mod GEMV | W retile (32-col slices) | bias table ----------------
// W tiled layout, flat elem per matrix:
//   i = s*12288 + (kt*4+g)*256 + ni*128 + r16*8 + j8
//   holds W[k = kt*32 + g*8 + j8][n = s*32 + ni*16 + r16]   (slice = 24 KB)

__global__ __launch_bounds__(256) void prep_all(
    const float* __restrict__ cond, const float* __restrict__ mw,
    const float* __restrict__ mb, float* __restrict__ mod,
    const float* __restrict__ qw, const float* __restrict__ kvw,
    const float* __restrict__ pw,
    bf16* __restrict__ wtq, bf16* __restrict__ wtkv, bf16* __restrict__ wtp,
    const float* __restrict__ tab, float* __restrict__ bT) {
  int bid = blockIdx.x, t = threadIdx.x;
  if (bid < 96) {                               // mod = cond @ mod_w + mod_b
    int idx = bid * 256 + t;                    // 24576 exact
    int b = idx / 768, j = idx % 768;
    float s = mb[j];
    const float* cr = cond + b * 128;
    #pragma unroll 4
    for (int k = 0; k < 128; k++) s += cr[k] * mw[(size_t)k * 768 + j];
    mod[idx] = s;
  } else if (bid < 2400) {                      // weight retile, 589824 exact
    int idx = (bid - 96) * 256 + t;
    const float* src; bf16* dst; int i, Wn;
    if (idx < 147456)      { i = idx;          src = qw;  dst = wtq;  Wn = 384; }
    else if (idx < 442368) { i = idx - 147456; src = kvw; dst = wtkv; Wn = 768; }
    else                   { i = idx - 442368; src = pw;  dst = wtp;  Wn = 384; }
    int s = i / 12288, rem = i % 12288;
    int u = rem >> 8, v = rem & 255;
    int ni = v >> 7, r16 = (v >> 3) & 15, j8 = v & 7;
    int kt = u >> 2, g = u & 3;
    int k = kt * 32 + g * 8 + j8, n = s * 32 + ni * 16 + r16;
    dst[i] = __float2bfloat16(src[(size_t)k * Wn + n]);
  } else {                                      // biasT[h][m][c], 49152 exact
    int idx = (bid - 2400) * 256 + t;
    int h = idx >> 12, rem = idx & 4095, m = rem >> 6, c = rem & 63;
    float v;
    if (c >= 49)      v = -1e30f;
    else if (m >= 49) v = 0.f;
    else {
      int yq = m / 7, xq = m % 7, yk = c / 7, xk = c % 7;
      v = tab[((yq - yk + 6) * 13 + (xq - xk + 6)) * 12 + h];
    }
    bT[idx] = v;
  }
}

// ---------------- LayerNorm (+AdaLN for x), row-major bf16 out, both streams ----------------

struct alignas(8) B4 { bf16 h[4]; };

__global__ __launch_bounds__(256) void ln_both(
    const float* __restrict__ x_tok, const float* __restrict__ gx,
    const float* __restrict__ bx, const float* __restrict__ modbuf,
    const float* __restrict__ z_tok, const float* __restrict__ gz,
    const float* __restrict__ bz,
    bf16* __restrict__ xO, bf16* __restrict__ zO) {
  int bid = blockIdx.x;
  bool isX = bid < 25088;
  const float* src   = isX ? x_tok : z_tok;
  const float* gamma = isX ? gx : gz;
  const float* beta  = isX ? bx : bz;
  const float* mod   = isX ? modbuf : nullptr;
  bf16* dst          = isX ? xO : zO;
  float eps          = isX ? 1e-6f : 1e-5f;
  int rb = (isX ? bid : bid - 25088) * 4;

  int wid = threadIdx.x >> 6, lane = threadIdx.x & 63;
  int r = rb + wid;
  int bb, ll; row_to_bl(r, bb, ll);
  const f32x4* x4 = (const f32x4*)(src + ((size_t)bb * LTOK + ll) * 384);
  f32x4 a = x4[lane];
  f32x4 b = {0.f, 0.f, 0.f, 0.f};
  if (lane < 32) b = x4[64 + lane];
  float s  = a[0] + a[1] + a[2] + a[3] + b[0] + b[1] + b[2] + b[3];
  float s2 = a[0]*a[0] + a[1]*a[1] + a[2]*a[2] + a[3]*a[3]
           + b[0]*b[0] + b[1]*b[1] + b[2]*b[2] + b[3]*b[3];
  #pragma unroll
  for (int d = 1; d < 64; d <<= 1) { s += __shfl_xor(s, d); s2 += __shfl_xor(s2, d); }
  float mu = s * (1.f / 384.f);
  float var = s2 * (1.f / 384.f) - mu * mu;
  float rstd = rsqrtf(var + eps);
  bf16* o = dst + (size_t)r * 384;
  const f32x4* g4 = (const f32x4*)gamma;
  const f32x4* be4 = (const f32x4*)beta;
  if (mod != nullptr) {
    const f32x4* mg4 = (const f32x4*)(mod + bb * 768);
    const f32x4* mb4 = (const f32x4*)(mod + bb * 768 + 384);
    {
      f32x4 gg = g4[lane], bb2 = be4[lane], mg = mg4[lane], mb = mb4[lane];
      B4 p;
      #pragma unroll
      for (int i = 0; i < 4; i++)
        p.h[i] = __float2bfloat16((gg[i] * (1.f + mg[i])) * ((a[i] - mu) * rstd) + bb2[i] + mb[i]);
      *((B4*)o + lane) = p;
    }
    if (lane < 32) {
      f32x4 gg = g4[64 + lane], bb2 = be4[64 + lane], mg = mg4[64 + lane], mb = mb4[64 + lane];
      B4 p;
      #pragma unroll
      for (int i = 0; i < 4; i++)
        p.h[i] = __float2bfloat16((gg[i] * (1.f + mg[i])) * ((b[i] - mu) * rstd) + bb2[i] + mb[i]);
      *((B4*)o + 64 + lane) = p;
    }
  } else {
    {
      f32x4 gg = g4[lane], bb2 = be4[lane];
      B4 p;
      #pragma unroll
      for (int i = 0; i < 4; i++)
        p.h[i] = __float2bfloat16((a[i] - mu) * rstd * gg[i] + bb2[i]);
      *((B4*)o + lane) = p;
    }
    if (lane < 32) {
      f32x4 gg = g4[64 + lane], bb2 = be4[64 + lane];
      B4 p;
      #pragma unroll
      for (int i = 0; i < 4; i++)
        p.h[i] = __float2bfloat16((b[i] - mu) * rstd * gg[i] + bb2[i]);
      *((B4*)o + 64 + lane) = p;
    }
  }
}

// ---------------- fused per-window kernel: q/kv proj + attention + out-proj ----------------
// Block = 1 window (49 rows), 4 waves. Wave handles 3 heads (rotated by blockIdx).
// LDS: x̂ [49][768B swz] | ẑ [49][768B swz] | per-wave {qS 4K, kS 4K, vS 4K, pS 8K}
// W streamed from L2 in the 32-col-slice tiled layout. q/kv/attn-out never touch HBM.

__global__ __launch_bounds__(256, 1) void fused_win(
    const bf16* __restrict__ xh, const bf16* __restrict__ zh,
    const bf16* __restrict__ wtq, const bf16* __restrict__ wtkv,
    const bf16* __restrict__ wtp,
    const float* __restrict__ qb, const float* __restrict__ kvb,
    const float* __restrict__ pb, const float* __restrict__ biasT,
    const float* __restrict__ resid, float* __restrict__ out) {
  __shared__ __align__(16) char L[157184];
  const int t = threadIdx.x, w = blockIdx.x;
  const int wid = t >> 6, lane = t & 63, r16 = lane & 15, g = lane >> 4;
  const f32x4 zero = {0.f, 0.f, 0.f, 0.f};

  // ---- stage x̂, ẑ window rows (XOR-swizzled 768B rows) ----
  for (int slot = t; slot < 4704; slot += 256) {
    int s = slot / 2352, rem = slot % 2352;
    int row = rem / 48, c8 = rem % 48;
    const bf16* src = (s ? zh : xh) + (size_t)(w * 49 + row) * 384 + c8 * 8;
    short8 v = *(const short8*)src;
    *(short8*)(L + s * 37632 + row * 768 + ((c8 * 16) ^ ((row & 7) << 4))) = v;
  }
  __syncthreads();

  const int hw = (wid + w) & 3;              // head-group rotation across blocks
  char* qS = L + 75264 + wid * 20480;
  char* kS = qS + 4096;
  char* vS = qS + 8192;                      // [32 ch][64 keys], 128B/ch
  char* pS = qS + 12288;                     // [64 rows][64 keys], 128B/row

  f32x4 pv[3][4][2] = {};                    // PV accs held across attn phase

  #pragma unroll
  for (int i = 0; i < 3; i++) {
    const int h = hw * 3 + i;

    // ---- q = x̂ @ Wq[:, h*32:+32] ----
    f32x4 qa[4][2] = {};
    #pragma unroll
    for (int kt = 0; kt < 12; kt++) {
      short8 xf[4];
      #pragma unroll
      for (int m = 0; m < 3; m++) {
        int row = m * 16 + r16;
        xf[m] = *(const short8*)(L + row * 768 + ((kt * 64 + g * 16) ^ ((row & 7) << 4)));
      }
      xf[3] = *(const short8*)(L + 48 * 768 + kt * 64 + g * 16);  // pad rows -> row 48
      const short8* wq = (const short8*)(wtq + (size_t)h * 12288 + (kt * 4 + g) * 256 + r16 * 8);
      short8 w0 = wq[0], w1 = wq[16];
      #pragma unroll
      for (int m = 0; m < 4; m++) {
        qa[m][0] = MFMA(xf[m], w0, qa[m][0]);
        qa[m][1] = MFMA(xf[m], w1, qa[m][1]);
      }
    }
    #pragma unroll
    for (int ni = 0; ni < 2; ni++) {
      float bc = qb[h * 32 + ni * 16 + r16];
      #pragma unroll
      for (int m = 0; m < 4; m++)
        #pragma unroll
        for (int rr = 0; rr < 4; rr++) {
          int row = m * 16 + g * 4 + rr;
          *(bf16*)(qS + row * 64 + (ni * 16 + r16) * 2) =
              __float2bfloat16((qa[m][ni][rr] + bc) * 0.17677669529663687f);
        }
    }

    // ---- k, v = ẑ @ Wkv[:, {h, 12+h} slices] ----
    f32x4 ka[4][2] = {}, va[4][2] = {};
    #pragma unroll
    for (int kt = 0; kt < 12; kt++) {
      short8 zf[4];
      #pragma unroll
      for (int m = 0; m < 3; m++) {
        int row = m * 16 + r16;
        zf[m] = *(const short8*)(L + 37632 + row * 768 + ((kt * 64 + g * 16) ^ ((row & 7) << 4)));
      }
      zf[3] = *(const short8*)(L + 37632 + 48 * 768 + kt * 64 + g * 16);
      const short8* wk = (const short8*)(wtkv + (size_t)h * 12288 + (kt * 4 + g) * 256 + r16 * 8);
      const short8* wv = (const short8*)(wtkv + (size_t)(12 + h) * 12288 + (kt * 4 + g) * 256 + r16 * 8);
      short8 k0 = wk[0], k1 = wk[16], v0 = wv[0], v1 = wv[16];
      #pragma unroll
      for (int m = 0; m < 4; m++) {
        ka[m][0] = MFMA(zf[m], k0, ka[m][0]);
        ka[m][1] = MFMA(zf[m], k1, ka[m][1]);
        va[m][0] = MFMA(zf[m], v0, va[m][0]);
        va[m][1] = MFMA(zf[m], v1, va[m][1]);
      }
    }
    #pragma unroll
    for (int ni = 0; ni < 2; ni++) {
      float bck = kvb[h * 32 + ni * 16 + r16];
      float bcv = kvb[384 + h * 32 + ni * 16 + r16];
      #pragma unroll
      for (int m = 0; m < 4; m++) {
        B4 pk;
        #pragma unroll
        for (int rr = 0; rr < 4; rr++) {
          int row = m * 16 + g * 4 + rr;
          *(bf16*)(kS + row * 64 + (ni * 16 + r16) * 2) = __float2bfloat16(ka[m][ni][rr] + bck);
          pk.h[rr] = __float2bfloat16(va[m][ni][rr] + bcv);
        }
        *(B4*)(vS + (ni * 16 + r16) * 128 + (m * 16 + g * 4) * 2) = pk;  // transposed store
      }
    }

    // ---- QK^T + bias + softmax -> pS ----
    short8 aq[4], bk[4];
    #pragma unroll
    for (int m = 0; m < 4; m++) aq[m] = *(const short8*)(qS + (m * 16 + r16) * 64 + g * 16);
    #pragma unroll
    for (int n = 0; n < 4; n++) bk[n] = *(const short8*)(kS + (n * 16 + r16) * 64 + g * 16);
    f32x4 S[4][4];
    #pragma unroll
    for (int m = 0; m < 4; m++)
      #pragma unroll
      for (int n = 0; n < 4; n++)
        S[m][n] = MFMA(aq[m], bk[n], zero);

    const float* bt = biasT + h * 4096;
    #pragma unroll
    for (int m = 0; m < 4; m++) {
      #pragma unroll
      for (int rr = 0; rr < 4; rr++) {
        int rowm = m * 16 + g * 4 + rr;
        float sv[4];
        #pragma unroll
        for (int n = 0; n < 4; n++)
          sv[n] = S[m][n][rr] + bt[rowm * 64 + n * 16 + r16];
        float mx = fmaxf(fmaxf(sv[0], sv[1]), fmaxf(sv[2], sv[3]));
        #pragma unroll
        for (int d = 1; d < 16; d <<= 1) mx = fmaxf(mx, __shfl_xor(mx, d));
        float sum = 0.f;
        #pragma unroll
        for (int n = 0; n < 4; n++) { sv[n] = __expf(sv[n] - mx); sum += sv[n]; }
        #pragma unroll
        for (int d = 1; d < 16; d <<= 1) sum += __shfl_xor(sum, d);
        float inv = __fdividef(1.f, sum);
        #pragma unroll
        for (int n = 0; n < 4; n++)
          *(bf16*)(pS + rowm * 128 + (n * 16 + r16) * 2) = __float2bfloat16(sv[n] * inv);
      }
    }

    // ---- PV ----
    #pragma unroll
    for (int c0 = 0; c0 < 2; c0++) {
      short8 pa[4], bv[2];
      #pragma unroll
      for (int m = 0; m < 4; m++)
        pa[m] = *(const short8*)(pS + (m * 16 + r16) * 128 + c0 * 64 + g * 16);
      #pragma unroll
      for (int d = 0; d < 2; d++)
        bv[d] = *(const short8*)(vS + (d * 16 + r16) * 128 + c0 * 64 + g * 16);
      #pragma unroll
      for (int m = 0; m < 4; m++)
        #pragma unroll
        for (int d = 0; d < 2; d++)
          pv[i][m][d] = MFMA(pa[m], bv[d], pv[i][m][d]);
    }
  }

  __syncthreads();                           // all waves done with x̂/ẑ
  // ---- attn-out -> LDS [49][768B swz] (reuse x̂ region) ----
  #pragma unroll
  for (int i = 0; i < 3; i++) {
    int h = hw * 3 + i;
    #pragma unroll
    for (int d = 0; d < 2; d++) {
      int col = h * 32 + d * 16 + r16;
      #pragma unroll
      for (int m = 0; m < 4; m++)
        #pragma unroll
        for (int rr = 0; rr < 4; rr++) {
          int row = m * 16 + g * 4 + rr;
          if (row < 49)
            *(bf16*)(L + row * 768 + ((col * 2) ^ ((row & 7) << 4))) =
                __float2bfloat16(pv[i][m][d][rr]);
        }
    }
  }
  __syncthreads();

  // ---- proj: out = attnout @ Wp + pb + resid, window-unpermuted f32 ----
  #pragma unroll
  for (int si = 0; si < 3; si++) {
    int sl = hw * 3 + si;                    // 32-col slice of Wp
    f32x4 ac[4][2] = {};
    #pragma unroll
    for (int kt = 0; kt < 12; kt++) {
      short8 af[4];
      #pragma unroll
      for (int m = 0; m < 4; m++) {
        int row = m * 16 + r16;              // rows 49-63 read stale (finite), masked below
        af[m] = *(const short8*)(L + row * 768 + ((kt * 64 + g * 16) ^ ((row & 7) << 4)));
      }
      const short8* wp = (const short8*)(wtp + (size_t)sl * 12288 + (kt * 4 + g) * 256 + r16 * 8);
      short8 p0 = wp[0], p1 = wp[16];
      #pragma unroll
      for (int m = 0; m < 4; m++) {
        ac[m][0] = MFMA(af[m], p0, ac[m][0]);
        ac[m][1] = MFMA(af[m], p1, ac[m][1]);
      }
    }
    #pragma unroll
    for (int ni = 0; ni < 2; ni++) {
      int col = sl * 32 + ni * 16 + r16;
      float bc = pb[col];
      #pragma unroll
      for (int m = 0; m < 4; m++)
        #pragma unroll
        for (int rr = 0; rr < 4; rr++) {
          int row = m * 16 + g * 4 + rr;
          if (row < 49) {
            int bb, ll; row_to_bl(w * 49 + row, bb, ll);
            size_t base = ((size_t)bb * LTOK + ll) * 384;
            out[base + col] = resid[base + col] + ac[m][ni][rr] + bc;
          }
        }
    }
  }
}

// ---------------- launch ----------------

extern "C" void kernel_launch(void* const* d_in, const int* in_sizes, int n_in,
                              void* d_out, int out_size, void* d_ws, size_t ws_size,
                              hipStream_t stream) {
  (void)in_sizes; (void)n_in; (void)out_size; (void)ws_size;
  const float* x_tok   = (const float*)d_in[0];
  const float* z_tok   = (const float*)d_in[1];
  const float* cond    = (const float*)d_in[2];
  const float* gamma_x = (const float*)d_in[3];
  const float* beta_x  = (const float*)d_in[4];
  const float* mod_w   = (const float*)d_in[5];
  const float* mod_b   = (const float*)d_in[6];
  const float* gamma_z = (const float*)d_in[7];
  const float* beta_z  = (const float*)d_in[8];
  const float* rel_tab = (const float*)d_in[9];
  const float* q_w     = (const float*)d_in[10];
  const float* q_b     = (const float*)d_in[11];
  const float* kv_w    = (const float*)d_in[12];
  const float* kv_b    = (const float*)d_in[13];
  const float* proj_w  = (const float*)d_in[14];
  const float* proj_b  = (const float*)d_in[15];

  char* ws = (char*)d_ws;
  float* modbuf = (float*)(ws + 0);                          //  98304 B
  bf16*  wtq    = (bf16*)(ws + 98304);                       // 294912 B (12 slices)
  bf16*  wtkv   = (bf16*)(ws + 98304 + 294912);              // 589824 B (24 slices)
  bf16*  wtp    = (bf16*)(ws + 98304 + 294912 + 589824);     // 294912 B (12 slices)
  float* biasT  = (float*)(ws + 98304 + 294912 + 589824 + 294912); // 196608 B
  bf16*  R1     = (bf16*)(ws + 1474560);                     // x̂ row-major (77 MB)
  bf16*  R4     = R1 + (size_t)MROWS * 384;                  // ẑ row-major (77 MB)

  prep_all<<<2592, 256, 0, stream>>>(cond, mod_w, mod_b, modbuf,
                                     q_w, kv_w, proj_w, wtq, wtkv, wtp,
                                     rel_tab, biasT);
  ln_both<<<50176, 256, 0, stream>>>(x_tok, gamma_x, beta_x, modbuf,
                                     z_tok, gamma_z, beta_z, R1, R4);
  fused_win<<<NWIN, 256, 0, stream>>>(R1, R4, wtq, wtkv, wtp,
                                      q_b, kv_b, proj_b, biasT,
                                      x_tok, (float*)d_out);
}

// Round 9
// 681.346 us; speedup vs baseline: 1.7269x; 1.1834x over previous
//
#include <hip/hip_runtime.h>
#include <hip/hip_bf16.h>

typedef float f32x4 __attribute__((ext_vector_type(4)));
typedef short short8 __attribute__((ext_vector_type(8)));
typedef __hip_bfloat16 bf16;

constexpr int LTOK  = 3136;      // 56*56
constexpr int NWIN  = 2048;
constexpr int MROWS = 100352;    // NWIN * 49
constexpr int MPAD  = MROWS + 64;

#define MFMA(a, b, c) __builtin_amdgcn_mfma_f32_16x16x32_bf16((a), (b), (c), 0, 0, 0)

// window-row r (w*49+n) -> (batch b, token l)
__device__ __forceinline__ void row_to_bl(int r, int& b, int& l) {
  int w = r / 49, n = r % 49;
  b = w >> 6;
  int wrem = w & 63;
  int wy = wrem >> 3, wx = wrem & 7;
  int ny = n / 7, nx = n % 7;
  l = (wy * 7 + ny) * 56 + wx * 7 + nx;
}

// ---------------- fused prep: mod GEMV | W retile (32-col slices) | bias table ----------------
// W tiled layout, flat elem per matrix:
//   i = s*12288 + (kt*4+g)*256 + ni*128 + r16*8 + j8
//   holds W[k = kt*32 + g*8 + j8][n = s*32 + ni*16 + r16]   (slice = 24 KB)

__global__ __launch_bounds__(256) void prep_all(
    const float* __restrict__ cond, const float* __restrict__ mw,
    const float* __restrict__ mb, float* __restrict__ mod,
    const float* __restrict__ qw, const float* __restrict__ kvw,
    const float* __restrict__ pw,
    bf16* __restrict__ wtq, bf16* __restrict__ wtkv, bf16* __restrict__ wtp,
    const float* __restrict__ tab, float* __restrict__ bT) {
  int bid = blockIdx.x, t = threadIdx.x;
  if (bid < 96) {                               // mod = cond @ mod_w + mod_b
    int idx = bid * 256 + t;                    // 24576 exact
    int b = idx / 768, j = idx % 768;
    float s = mb[j];
    const float* cr = cond + b * 128;
    #pragma unroll 4
    for (int k = 0; k < 128; k++) s += cr[k] * mw[(size_t)k * 768 + j];
    mod[idx] = s;
  } else if (bid < 2400) {                      // weight retile, 589824 exact
    int idx = (bid - 96) * 256 + t;
    const float* src; bf16* dst; int i, Wn;
    if (idx < 147456)      { i = idx;          src = qw;  dst = wtq;  Wn = 384; }
    else if (idx < 442368) { i = idx - 147456; src = kvw; dst = wtkv; Wn = 768; }
    else                   { i = idx - 442368; src = pw;  dst = wtp;  Wn = 384; }
    int s = i / 12288, rem = i % 12288;
    int u = rem >> 8, v = rem & 255;
    int ni = v >> 7, r16 = (v >> 3) & 15, j8 = v & 7;
    int kt = u >> 2, g = u & 3;
    int k = kt * 32 + g * 8 + j8, n = s * 32 + ni * 16 + r16;
    dst[i] = __float2bfloat16(src[(size_t)k * Wn + n]);
  } else {                                      // biasT[h][m][c], 49152 exact
    int idx = (bid - 2400) * 256 + t;
    int h = idx >> 12, rem = idx & 4095, m = rem >> 6, c = rem & 63;
    float v;
    if (c >= 49)      v = -1e30f;
    else if (m >= 49) v = 0.f;
    else {
      int yq = m / 7, xq = m % 7, yk = c / 7, xk = c % 7;
      v = tab[((yq - yk + 6) * 13 + (xq - xk + 6)) * 12 + h];
    }
    bT[idx] = v;
  }
}

// ---------------- LayerNorm (+AdaLN for x), row-major bf16 out, both streams ----------------

struct alignas(8) B4 { bf16 h[4]; };

__global__ __launch_bounds__(256) void ln_both(
    const float* __restrict__ x_tok, const float* __restrict__ gx,
    const float* __restrict__ bx, const float* __restrict__ modbuf,
    const float* __restrict__ z_tok, const float* __restrict__ gz,
    const float* __restrict__ bz,
    bf16* __restrict__ xO, bf16* __restrict__ zO) {
  int bid = blockIdx.x;
  bool isX = bid < 25088;
  const float* src   = isX ? x_tok : z_tok;
  const float* gamma = isX ? gx : gz;
  const float* beta  = isX ? bx : bz;
  const float* mod   = isX ? modbuf : nullptr;
  bf16* dst          = isX ? xO : zO;
  float eps          = isX ? 1e-6f : 1e-5f;
  int rb = (isX ? bid : bid - 25088) * 4;

  int wid = threadIdx.x >> 6, lane = threadIdx.x & 63;
  int r = rb + wid;
  int bb, ll; row_to_bl(r, bb, ll);
  const f32x4* x4 = (const f32x4*)(src + ((size_t)bb * LTOK + ll) * 384);
  f32x4 a = x4[lane];
  f32x4 b = {0.f, 0.f, 0.f, 0.f};
  if (lane < 32) b = x4[64 + lane];
  float s  = a[0] + a[1] + a[2] + a[3] + b[0] + b[1] + b[2] + b[3];
  float s2 = a[0]*a[0] + a[1]*a[1] + a[2]*a[2] + a[3]*a[3]
           + b[0]*b[0] + b[1]*b[1] + b[2]*b[2] + b[3]*b[3];
  #pragma unroll
  for (int d = 1; d < 64; d <<= 1) { s += __shfl_xor(s, d); s2 += __shfl_xor(s2, d); }
  float mu = s * (1.f / 384.f);
  float var = s2 * (1.f / 384.f) - mu * mu;
  float rstd = rsqrtf(var + eps);
  bf16* o = dst + (size_t)r * 384;
  const f32x4* g4 = (const f32x4*)gamma;
  const f32x4* be4 = (const f32x4*)beta;
  if (mod != nullptr) {
    const f32x4* mg4 = (const f32x4*)(mod + bb * 768);
    const f32x4* mb4 = (const f32x4*)(mod + bb * 768 + 384);
    {
      f32x4 gg = g4[lane], bb2 = be4[lane], mg = mg4[lane], mb = mb4[lane];
      B4 p;
      #pragma unroll
      for (int i = 0; i < 4; i++)
        p.h[i] = __float2bfloat16((gg[i] * (1.f + mg[i])) * ((a[i] - mu) * rstd) + bb2[i] + mb[i]);
      *((B4*)o + lane) = p;
    }
    if (lane < 32) {
      f32x4 gg = g4[64 + lane], bb2 = be4[64 + lane], mg = mg4[64 + lane], mb = mb4[64 + lane];
      B4 p;
      #pragma unroll
      for (int i = 0; i < 4; i++)
        p.h[i] = __float2bfloat16((gg[i] * (1.f + mg[i])) * ((b[i] - mu) * rstd) + bb2[i] + mb[i]);
      *((B4*)o + 64 + lane) = p;
    }
  } else {
    {
      f32x4 gg = g4[lane], bb2 = be4[lane];
      B4 p;
      #pragma unroll
      for (int i = 0; i < 4; i++)
        p.h[i] = __float2bfloat16((a[i] - mu) * rstd * gg[i] + bb2[i]);
      *((B4*)o + lane) = p;
    }
    if (lane < 32) {
      f32x4 gg = g4[64 + lane], bb2 = be4[64 + lane];
      B4 p;
      #pragma unroll
      for (int i = 0; i < 4; i++)
        p.h[i] = __float2bfloat16((b[i] - mu) * rstd * gg[i] + bb2[i]);
      *((B4*)o + 64 + lane) = p;
    }
  }
}

// ---------------- fused per-window kernel v2: 58 KB LDS, 2 blocks/CU ----------------
// Block = 1 window, 4 waves, wave handles 3 heads (rotated by blockIdx).
// x̂/ẑ fragments read DIRECTLY from global (L2-hot). Per-wave bounce buffers with
// conflict-free strides (80/144 B). P overlays q/k; attn-out overlays wave buffers.

constexpr int WVB = 14848;        // per-wave buffer bytes: qS 5120 | kS 5120 | vS 4608

__global__ __launch_bounds__(256, 2) void fused_win(
    const bf16* __restrict__ xh, const bf16* __restrict__ zh,
    const bf16* __restrict__ wtq, const bf16* __restrict__ wtkv,
    const bf16* __restrict__ wtp,
    const float* __restrict__ qb, const float* __restrict__ kvb,
    const float* __restrict__ pb, const float* __restrict__ biasT,
    const float* __restrict__ resid, float* __restrict__ out) {
  __shared__ __align__(16) char L[4 * WVB];     // 59392 B
  const int t = threadIdx.x, w = blockIdx.x;
  const int wid = t >> 6, lane = t & 63, r16 = lane & 15, g = lane >> 4;
  const f32x4 zero = {0.f, 0.f, 0.f, 0.f};

  char* qS = L + wid * WVB;                     // 64 rows x 80 B
  char* kS = qS + 5120;                         // 64 rows x 80 B
  char* vS = qS + 10240;                        // 32 ch  x 144 B
  char* pS = qS;                                // P overlays q/k: 64 x 144 B = 9216

  const bf16* xw = xh + (size_t)w * 49 * 384;   // window rows (may run 15 rows past; padded)
  const bf16* zw = zh + (size_t)w * 49 * 384;

  const int hw = (wid + w) & 3;                 // head-group rotation across waves/blocks
  f32x4 pv[3][4][2] = {};

  #pragma unroll
  for (int i = 0; i < 3; i++) {
    const int h = hw * 3 + i;

    // ---- q = x̂ @ Wq slice h ----
    f32x4 qa[4][2] = {};
    #pragma unroll
    for (int kt = 0; kt < 12; kt++) {
      short8 xf[4];
      #pragma unroll
      for (int m = 0; m < 4; m++)
        xf[m] = *(const short8*)(xw + (size_t)(m * 16 + r16) * 384 + kt * 32 + g * 8);
      const short8* wq = (const short8*)(wtq + (size_t)h * 12288 + (kt * 4 + g) * 256 + r16 * 8);
      short8 w0 = wq[0], w1 = wq[16];
      #pragma unroll
      for (int m = 0; m < 4; m++) {
        qa[m][0] = MFMA(xf[m], w0, qa[m][0]);
        qa[m][1] = MFMA(xf[m], w1, qa[m][1]);
      }
    }
    #pragma unroll
    for (int ni = 0; ni < 2; ni++) {
      float bc = qb[h * 32 + ni * 16 + r16];
      #pragma unroll
      for (int m = 0; m < 4; m++)
        #pragma unroll
        for (int rr = 0; rr < 4; rr++) {
          int row = m * 16 + g * 4 + rr;
          *(bf16*)(qS + row * 80 + (ni * 16 + r16) * 2) =
              __float2bfloat16((qa[m][ni][rr] + bc) * 0.17677669529663687f);
        }
    }

    // ---- k, v = ẑ @ Wkv slices {h, 12+h} ----
    f32x4 ka[4][2] = {}, va[4][2] = {};
    #pragma unroll
    for (int kt = 0; kt < 12; kt++) {
      short8 zf[4];
      #pragma unroll
      for (int m = 0; m < 4; m++)
        zf[m] = *(const short8*)(zw + (size_t)(m * 16 + r16) * 384 + kt * 32 + g * 8);
      const short8* wk = (const short8*)(wtkv + (size_t)h * 12288 + (kt * 4 + g) * 256 + r16 * 8);
      const short8* wv = (const short8*)(wtkv + (size_t)(12 + h) * 12288 + (kt * 4 + g) * 256 + r16 * 8);
      short8 k0 = wk[0], k1 = wk[16], v0 = wv[0], v1 = wv[16];
      #pragma unroll
      for (int m = 0; m < 4; m++) {
        ka[m][0] = MFMA(zf[m], k0, ka[m][0]);
        ka[m][1] = MFMA(zf[m], k1, ka[m][1]);
        va[m][0] = MFMA(zf[m], v0, va[m][0]);
        va[m][1] = MFMA(zf[m], v1, va[m][1]);
      }
    }
    #pragma unroll
    for (int ni = 0; ni < 2; ni++) {
      float bck = kvb[h * 32 + ni * 16 + r16];
      float bcv = kvb[384 + h * 32 + ni * 16 + r16];
      #pragma unroll
      for (int m = 0; m < 4; m++) {
        B4 pk;
        #pragma unroll
        for (int rr = 0; rr < 4; rr++) {
          int row = m * 16 + g * 4 + rr;
          *(bf16*)(kS + row * 80 + (ni * 16 + r16) * 2) = __float2bfloat16(ka[m][ni][rr] + bck);
          pk.h[rr] = __float2bfloat16(va[m][ni][rr] + bcv);
        }
        *(B4*)(vS + (ni * 16 + r16) * 144 + (m * 16 + g * 4) * 2) = pk;  // V^T store
      }
    }

    // ---- QK^T + bias + softmax -> pS (overlays q/k; DS ops are in-order per wave) ----
    short8 aq[4], bk[4];
    #pragma unroll
    for (int m = 0; m < 4; m++) aq[m] = *(const short8*)(qS + (m * 16 + r16) * 80 + g * 16);
    #pragma unroll
    for (int n = 0; n < 4; n++) bk[n] = *(const short8*)(kS + (n * 16 + r16) * 80 + g * 16);
    f32x4 S[4][4];
    #pragma unroll
    for (int m = 0; m < 4; m++)
      #pragma unroll
      for (int n = 0; n < 4; n++)
        S[m][n] = MFMA(aq[m], bk[n], zero);

    const float* bt = biasT + h * 4096;
    #pragma unroll
    for (int m = 0; m < 4; m++) {
      #pragma unroll
      for (int rr = 0; rr < 4; rr++) {
        int rowm = m * 16 + g * 4 + rr;
        float sv[4];
        #pragma unroll
        for (int n = 0; n < 4; n++)
          sv[n] = S[m][n][rr] + bt[rowm * 64 + n * 16 + r16];
        float mx = fmaxf(fmaxf(sv[0], sv[1]), fmaxf(sv[2], sv[3]));
        #pragma unroll
        for (int d = 1; d < 16; d <<= 1) mx = fmaxf(mx, __shfl_xor(mx, d));
        float sum = 0.f;
        #pragma unroll
        for (int n = 0; n < 4; n++) { sv[n] = __expf(sv[n] - mx); sum += sv[n]; }
        #pragma unroll
        for (int d = 1; d < 16; d <<= 1) sum += __shfl_xor(sum, d);
        float inv = __fdividef(1.f, sum);
        #pragma unroll
        for (int n = 0; n < 4; n++)
          *(bf16*)(pS + rowm * 144 + (n * 16 + r16) * 2) = __float2bfloat16(sv[n] * inv);
      }
    }

    // ---- PV ----
    #pragma unroll
    for (int c0 = 0; c0 < 2; c0++) {
      short8 pa[4], bv[2];
      #pragma unroll
      for (int m = 0; m < 4; m++)
        pa[m] = *(const short8*)(pS + (m * 16 + r16) * 144 + c0 * 64 + g * 16);
      #pragma unroll
      for (int d = 0; d < 2; d++)
        bv[d] = *(const short8*)(vS + (d * 16 + r16) * 144 + c0 * 64 + g * 16);
      #pragma unroll
      for (int m = 0; m < 4; m++)
        #pragma unroll
        for (int d = 0; d < 2; d++)
          pv[i][m][d] = MFMA(pa[m], bv[d], pv[i][m][d]);
    }
  }

  __syncthreads();                              // wave buffers dead; reuse L for attn-out
  // ---- attn-out -> L [49 rows][768 B, XOR-swizzled] ----
  #pragma unroll
  for (int i = 0; i < 3; i++) {
    int h = hw * 3 + i;
    #pragma unroll
    for (int d = 0; d < 2; d++) {
      int col = h * 32 + d * 16 + r16;
      #pragma unroll
      for (int m = 0; m < 4; m++)
        #pragma unroll
        for (int rr = 0; rr < 4; rr++) {
          int row = m * 16 + g * 4 + rr;
          if (row < 49)
            *(bf16*)(L + row * 768 + ((col * 2) ^ ((row & 7) << 4))) =
                __float2bfloat16(pv[i][m][d][rr]);
        }
    }
  }
  __syncthreads();

  // ---- proj: out = attnout @ Wp + pb + resid, window-unpermuted f32 ----
  #pragma unroll
  for (int si = 0; si < 3; si++) {
    int sl = hw * 3 + si;
    f32x4 ac[4][2] = {};
    #pragma unroll
    for (int kt = 0; kt < 12; kt++) {
      short8 af[4];
      #pragma unroll
      for (int m = 0; m < 4; m++) {
        int row = m * 16 + r16;                 // rows 49..63 read garbage-but-finite LDS
        af[m] = *(const short8*)(L + row * 768 + ((kt * 64 + g * 16) ^ ((row & 7) << 4)));
      }
      const short8* wp = (const short8*)(wtp + (size_t)sl * 12288 + (kt * 4 + g) * 256 + r16 * 8);
      short8 p0 = wp[0], p1 = wp[16];
      #pragma unroll
      for (int m = 0; m < 4; m++) {
        ac[m][0] = MFMA(af[m], p0, ac[m][0]);
        ac[m][1] = MFMA(af[m], p1, ac[m][1]);
      }
    }
    #pragma unroll
    for (int ni = 0; ni < 2; ni++) {
      int col = sl * 32 + ni * 16 + r16;
      float bc = pb[col];
      #pragma unroll
      for (int m = 0; m < 4; m++)
        #pragma unroll
        for (int rr = 0; rr < 4; rr++) {
          int row = m * 16 + g * 4 + rr;
          if (row < 49) {
            int bb, ll; row_to_bl(w * 49 + row, bb, ll);
            size_t base = ((size_t)bb * LTOK + ll) * 384;
            out[base + col] = resid[base + col] + ac[m][ni][rr] + bc;
          }
        }
    }
  }
}

// ---------------- launch ----------------

extern "C" void kernel_launch(void* const* d_in, const int* in_sizes, int n_in,
                              void* d_out, int out_size, void* d_ws, size_t ws_size,
                              hipStream_t stream) {
  (void)in_sizes; (void)n_in; (void)out_size; (void)ws_size;
  const float* x_tok   = (const float*)d_in[0];
  const float* z_tok   = (const float*)d_in[1];
  const float* cond    = (const float*)d_in[2];
  const float* gamma_x = (const float*)d_in[3];
  const float* beta_x  = (const float*)d_in[4];
  const float* mod_w   = (const float*)d_in[5];
  const float* mod_b   = (const float*)d_in[6];
  const float* gamma_z = (const float*)d_in[7];
  const float* beta_z  = (const float*)d_in[8];
  const float* rel_tab = (const float*)d_in[9];
  const float* q_w     = (const float*)d_in[10];
  const float* q_b     = (const float*)d_in[11];
  const float* kv_w    = (const float*)d_in[12];
  const float* kv_b    = (const float*)d_in[13];
  const float* proj_w  = (const float*)d_in[14];
  const float* proj_b  = (const float*)d_in[15];

  char* ws = (char*)d_ws;
  float* modbuf = (float*)(ws + 0);                          //  98304 B
  bf16*  wtq    = (bf16*)(ws + 98304);                       // 294912 B (12 slices)
  bf16*  wtkv   = (bf16*)(ws + 98304 + 294912);              // 589824 B (24 slices)
  bf16*  wtp    = (bf16*)(ws + 98304 + 294912 + 589824);     // 294912 B (12 slices)
  float* biasT  = (float*)(ws + 98304 + 294912 + 589824 + 294912); // 196608 B
  bf16*  R1     = (bf16*)(ws + 1474560);                     // x̂ row-major, MPAD rows
  bf16*  R4     = R1 + (size_t)MPAD * 384;                   // ẑ row-major, MPAD rows

  // zero pad rows (fragment reads run up to 15 rows past the last window)
  hipMemsetAsync(R1 + (size_t)MROWS * 384, 0, 64 * 384 * 2, stream);
  hipMemsetAsync(R4 + (size_t)MROWS * 384, 0, 64 * 384 * 2, stream);

  prep_all<<<2592, 256, 0, stream>>>(cond, mod_w, mod_b, modbuf,
                                     q_w, kv_w, proj_w, wtq, wtkv, wtp,
                                     rel_tab, biasT);
  ln_both<<<50176, 256, 0, stream>>>(x_tok, gamma_x, beta_x, modbuf,
                                     z_tok, gamma_z, beta_z, R1, R4);
  fused_win<<<NWIN, 256, 0, stream>>>(R1, R4, wtq, wtkv, wtp,
                                      q_b, kv_b, proj_b, biasT,
                                      x_tok, (float*)d_out);
}